// Round 10
// baseline (36.242 us; speedup 1.0000x reference)
//
#include <hip/hip_runtime.h>
#include <stdint.h>

// MosaicSDF: N=1024 points, G=512 grids, K=7 (343 nodes/grid).
// R10: single kernel, block (256 thr = 4 waves) per point.
//   Phase 1: wave w sweeps grids [w*128,(w+1)*128) (2 ballot rounds),
//     centers/scales pre-staged in LDS (aliased with row buffer);
//     ballot-scan compacts active (rx,ry,rz,gwr)+gid per wave segment.
//   Phase 2: 16-lane group per active pair (16 pairs/chunk). Row staged
//     via 6 ALIGNED dwordx4 loads/lane of the covering 16B window (d0
//     fold on the read base) -> rbuf[6] = 24 VGPRs (R8/R9 spilled with
//     44+). LDS pitch 89 blocks (356 dw = 4 mod 32) de-aliases groups.
//     Lane computes rows {sub,sub+16,sub+32} (7 nodes each) + row-48
//     tail; 4-step group reduce. Software-pipelined. No lambdas, no
//     struct returns, no asm waits, no atomics, no workspace.

#define NPTS     1024
#define NGRIDS   512
#define TPB      256
#define NW       4
#define NGRP     16
#define ROWBYTES 1372          // 343 floats
#define ROWPITCH 89            // uint4 blocks per staged row (1424 B)
#define STEP     (1.0f / 6.0f)
#define FSQRT(x) __builtin_amdgcn_sqrtf(x)

__global__ __launch_bounds__(TPB) void msdf_fused(
    const float* __restrict__ points,    // (N,3)
    const float* __restrict__ centers,   // (G,3)
    const float* __restrict__ scales,    // (G,)
    const float* __restrict__ vals,      // (G,343)
    float* __restrict__ out)             // (N,)
{
    __shared__ uint4  s_v[NGRP][ROWPITCH];    // 22,784 B staged rows
    __shared__ float4 s_pair[NW][128];        // (rx,ry,rz,gwr) per active
    __shared__ unsigned short s_gid[NW][128];
    __shared__ int   s_c[NW];
    __shared__ float s_d[NW];
    __shared__ float s_a[NW];

    const int n    = blockIdx.x;
    const int t    = threadIdx.x;
    const int w    = t >> 6;
    const int lane = t & 63;
    const int grp  = t >> 4;             // 0..15 (4 groups per wave)
    const int sub  = t & 15;

    // Stage centers(384 float4)+scales(128 float4) into LDS alias of s_v.
    float* s_cen = (float*)&s_v[0][0];   // 1536 floats
    float* s_scl = s_cen + 1536;         // 512 floats
    {
        const float4* c4 = (const float4*)centers;
        const float4* s4 = (const float4*)scales;
        float4* dst = (float4*)s_cen;
        dst[t]           = (t < 384) ? c4[t] : s4[t - 384];
        const int u = t + 256;
        dst[u]           = (u < 384) ? c4[u] : s4[u - 384];
    }
    const float px = points[n * 3 + 0];  // uniform -> scalar loads
    const float py = points[n * 3 + 1];
    const float pz = points[n * 3 + 2];
    __syncthreads();

    // ---- Phase 1: activity sweep + ballot-scan compaction ----
    float dsum  = 0.0f;
    int   cbase = 0;
    #pragma unroll
    for (int r = 0; r < 2; ++r) {
        const int g = w * 128 + r * 64 + lane;
        const float invs = 1.0f / s_scl[g];
        const float rx = (px - s_cen[g * 3 + 0]) * invs;
        const float ry = (py - s_cen[g * 3 + 1]) * invs;
        const float rz = (pz - s_cen[g * 3 + 2]) * invs;
        const float gwr = 1.0f - FSQRT(rx * rx + ry * ry + rz * rz);
        const bool  act = (gwr > 0.0f);
        const unsigned long long m = __ballot(act);
        if (act) {
            const int pos = cbase + (int)__popcll(m & ((1ull << lane) - 1ull));
            s_pair[w][pos] = make_float4(rx, ry, rz, gwr);
            s_gid[w][pos]  = (unsigned short)g;
            dsum += gwr;
        }
        cbase += (int)__popcll(m);
    }
    #pragma unroll
    for (int off = 32; off >= 1; off >>= 1) dsum += __shfl_xor(dsum, off);
    if (lane == 0) { s_c[w] = cbase; s_d[w] = dsum; }
    __syncthreads();                     // also closes s_cen/s_scl alias use

    const int off1 = s_c[0];
    const int off2 = off1 + s_c[1];
    const int off3 = off2 + s_c[2];
    const int C    = off3 + s_c[3];
    const float den = s_d[0] + s_d[1] + s_d[2] + s_d[3];

    // ---- Phase 2: 16-lane group per pair, aligned-x4 staging ----
    float acc = 0.0f;
    if (C > 0) {
        const int nch = (C + NGRP - 1) >> 4;
        uint4 rbuf[6];
        float4 pr;
        int    gid;

        // -- prologue fetch: pair `grp`, then its row --
        {
            const int pc  = (grp < C) ? grp : (C - 1);
            const int seg = (pc >= off1) + (pc >= off2) + (pc >= off3);
            const int b0  = (seg == 0) ? 0 : (seg == 1) ? off1
                          : (seg == 2) ? off2 : off3;
            pr  = s_pair[seg][pc - b0];
            gid = (int)s_gid[seg][pc - b0];
        }
        {
            const int rb    = gid * ROWBYTES;
            const int d0    = rb & 15;
            const int lastb = (d0 + ROWBYTES - 1) >> 4;      // <= 86
            const uint4* __restrict__ src =
                (const uint4*)((const char*)vals + (rb & ~15));
            #pragma unroll
            for (int k = 0; k < 6; ++k) {
                const int b  = sub + 16 * k;
                const int bc = (b < lastb) ? b : lastb;
                rbuf[k] = src[bc];
            }
        }

        for (int c = 0; c < nch; ++c) {
            // Commit staged row (chunk c) to this group's LDS region.
            #pragma unroll
            for (int k = 0; k < 6; ++k) {
                const int b = sub + 16 * k;
                if (b <= 86) s_v[grp][b] = rbuf[k];
            }
            const float4 prc  = pr;
            const int    gidc = gid;
            const float  gw   = (c * NGRP + grp < C) ? prc.w : 0.0f;

            // Prefetch next chunk's pair+row while computing this one.
            if (c + 1 < nch) {
                const int p   = (c + 1) * NGRP + grp;
                const int pc  = (p < C) ? p : (C - 1);
                const int seg = (pc >= off1) + (pc >= off2) + (pc >= off3);
                const int b0  = (seg == 0) ? 0 : (seg == 1) ? off1
                              : (seg == 2) ? off2 : off3;
                pr  = s_pair[seg][pc - b0];
                gid = (int)s_gid[seg][pc - b0];
                const int rb    = gid * ROWBYTES;
                const int d0    = rb & 15;
                const int lastb = (d0 + ROWBYTES - 1) >> 4;
                const uint4* __restrict__ src =
                    (const uint4*)((const char*)vals + (rb & ~15));
                #pragma unroll
                for (int k = 0; k < 6; ++k) {
                    const int b  = sub + 16 * k;
                    const int bc = (b < lastb) ? b : lastb;
                    rbuf[k] = src[bc];
                }
            }

            // Read base: fold row's 16B misalignment into the offset.
            const int dd = (gidc * ROWBYTES) & 15;
            const float* __restrict__ myrow =
                (const float*)&s_v[grp][0] + (dd >> 2);

            float dz2[7];
            #pragma unroll
            for (int l = 0; l < 7; ++l) {
                const float d = prc.z - l * STEP;
                dz2[l] = d * d;
            }

            float ws = 0.0f, vs = 0.0f;
            #pragma unroll
            for (int rr = 0; rr < 3; ++rr) {
                const int rowid = sub + 16 * rr;             // 0..47
                const int i = (rowid * 9363) >> 16;          // rowid / 7
                const int j = rowid - i * 7;
                const float dxv = prc.x - (float)i * STEP;
                const float dyv = prc.y - (float)j * STEP;
                const float dxy = dxv * dxv + dyv * dyv;
                const float* __restrict__ vr = myrow + rowid * 7;
                #pragma unroll
                for (int l = 0; l < 7; ++l) {
                    const float d2 = dxy + dz2[l];
                    const float wt = (d2 <= 1.0f) ? FSQRT(d2) : 0.0f;
                    ws += wt;
                    vs  = fmaf(wt, vr[l], vs);
                }
            }
            if (sub < 7) {                                   // row 48: (6,6,sub)
                const float dxv = prc.x - 1.0f;
                const float dyv = prc.y - 1.0f;
                const float dzv = prc.z - (float)sub * STEP;
                const float d2  = dxv * dxv + dyv * dyv + dzv * dzv;
                const float wt  = (d2 <= 1.0f) ? FSQRT(d2) : 0.0f;
                ws += wt;
                vs  = fmaf(wt, myrow[336 + sub], vs);
            }
            #pragma unroll
            for (int o = 8; o >= 1; o >>= 1) {
                ws += __shfl_xor(ws, o);
                vs += __shfl_xor(vs, o);
            }
            const float interp = (ws > 0.0f) ? (vs / ws) : 0.0f;
            if (sub == 0) acc += interp * gw;
        }
    }

    // Block reduction (sub==0 lanes hold group partials).
    #pragma unroll
    for (int o = 32; o >= 1; o >>= 1) acc += __shfl_xor(acc, o);
    if (lane == 0) s_a[w] = acc;
    __syncthreads();
    if (t == 0) {
        const float ns = s_a[0] + s_a[1] + s_a[2] + s_a[3];
        out[n] = (den > 0.0f) ? (ns / den) : 0.0f;
    }
}

extern "C" void kernel_launch(void* const* d_in, const int* in_sizes, int n_in,
                              void* d_out, int out_size, void* d_ws, size_t ws_size,
                              hipStream_t stream) {
    const float* points  = (const float*)d_in[0];   // (1024,3)
    const float* centers = (const float*)d_in[1];   // (512,3)
    const float* scales  = (const float*)d_in[2];   // (512,)
    const float* vals    = (const float*)d_in[3];   // (512,7,7,7)
    float* out = (float*)d_out;                     // (1024,)

    msdf_fused<<<NPTS, TPB, 0, stream>>>(points, centers, scales, vals, out);
}

// Round 12
// 16.057 us; speedup vs baseline: 2.2571x; 2.2571x over previous
//
#include <hip/hip_runtime.h>

// MosaicSDF: N=1024 points, G=512 grids, K=7 (343 nodes/grid).
// R12 = R7 (proven 17us, absmax 0) + straggler pooling: block = 2 points.
//   512 blocks x 256 thr (4 waves). Phase 1: wave w sweeps 256 grids for
//   point w>>1 (4 ballot rounds), centers/scales pre-staged in LDS (alias
//   of the row buffer); ballot-scan compacts (rx,ry,rz,gwr)+gid per wave
//   segment. Phase 2: the 32 8-lane groups drain the COMBINED pair pool
//   of both points (CT = C0+C1) with R7's exact staging/compute: scalar
//   float rbuf[43] (the only non-spilling variant), software-pipelined
//   prefetch, lane sub = x-slab, static dy2/dz2 register tables, 3-step
//   group reduce; contribution routed to acc0/acc1 by segment (predicated
//   scalar adds). No atomics, no workspace, one dispatch.

#define NPTS   1024
#define NGRIDS 512
#define TPB    256
#define NBLK   512             // 2 points per block
#define ROWF   344             // LDS row pitch in floats (343 + 1 pad)
#define STEP   (1.0f / 6.0f)
#define FSQRT(x) __builtin_amdgcn_sqrtf(x)

__global__ __launch_bounds__(TPB) void msdf_fused(
    const float* __restrict__ points,    // (N,3)
    const float* __restrict__ centers,   // (G,3)
    const float* __restrict__ scales,    // (G,)
    const float* __restrict__ vals,      // (G,343)
    float* __restrict__ out)             // (N,)
{
    __shared__ float  s_v[32][ROWF];          // 44,032 B rows (alias cen/scl)
    __shared__ float4 s_pair[4][256];         // 16,384 B (rx,ry,rz,gwr)
    __shared__ unsigned short s_gid[4][256];  // 2,048 B
    __shared__ int   s_c[4];
    __shared__ float s_d[4];
    __shared__ float s_red[4][2];

    const int bid  = blockIdx.x;
    const int t    = threadIdx.x;
    const int w    = t >> 6;             // wave 0..3
    const int lane = t & 63;
    const int grp  = t >> 3;             // 0..31: 8-lane group (pair slot)
    const int sub  = t & 7;

    // Stage centers (384 float4) + scales (128 float4) into alias of s_v.
    float* s_cen = &s_v[0][0];           // 1536 floats
    float* s_scl = s_cen + 1536;         // 512 floats
    {
        float4* dst = (float4*)s_cen;
        const float4* c4 = (const float4*)centers;
        const float4* s4 = (const float4*)scales;
        dst[t] = (t < 384) ? c4[t] : s4[t - 384];
        const int u = t + 256;
        dst[u] = (u < 384) ? c4[u] : s4[u - 384];
    }

    const int   p  = w >> 1;             // this wave's point (0 or 1)
    const int   n  = (bid << 1) + p;
    const float px = points[n * 3 + 0];  // wave-uniform -> scalar loads
    const float py = points[n * 3 + 1];
    const float pz = points[n * 3 + 2];
    __syncthreads();

    // ---- Phase 1: activity sweep + ballot-scan compaction ----
    float dsum  = 0.0f;
    int   cbase = 0;
    #pragma unroll
    for (int r = 0; r < 4; ++r) {
        const int g = ((w & 1) << 8) + (r << 6) + lane;   // this wave's 256 grids
        const float invs = 1.0f / s_scl[g];
        const float rx = (px - s_cen[g * 3 + 0]) * invs;
        const float ry = (py - s_cen[g * 3 + 1]) * invs;
        const float rz = (pz - s_cen[g * 3 + 2]) * invs;
        const float gwr = 1.0f - FSQRT(rx * rx + ry * ry + rz * rz);
        const bool  act = (gwr > 0.0f);
        const unsigned long long m = __ballot(act);
        if (act) {
            const int pos = cbase + (int)__popcll(m & ((1ull << lane) - 1ull));
            s_pair[w][pos] = make_float4(rx, ry, rz, gwr);
            s_gid[w][pos]  = (unsigned short)g;
            dsum += gwr;
        }
        cbase += (int)__popcll(m);
    }
    #pragma unroll
    for (int o = 32; o >= 1; o >>= 1) dsum += __shfl_xor(dsum, o);
    if (lane == 0) { s_c[w] = cbase; s_d[w] = dsum; }
    __syncthreads();                     // also closes s_cen/s_scl alias use

    const int o1 = s_c[0];
    const int o2 = o1 + s_c[1];
    const int o3 = o2 + s_c[2];
    const int CT = o3 + s_c[3];
    const float den0 = s_d[0] + s_d[1];
    const float den1 = s_d[2] + s_d[3];

    // ---- Phase 2: 32 groups drain the combined pool, R7 staging ----
    float acc0 = 0.0f, acc1 = 0.0f;
    if (CT > 0) {
        const int nch = (CT + 31) >> 5;
        float  rbuf[43];
        float4 pr;
        int    gid, seg;

        #define FETCH(a_) {                                               \
            const int pc = ((a_) < CT) ? (a_) : (CT - 1);                 \
            seg = (pc >= o1) + (pc >= o2) + (pc >= o3);                   \
            const int b0 = (seg == 0) ? 0 : (seg == 1) ? o1               \
                         : (seg == 2) ? o2 : o3;                          \
            pr  = s_pair[seg][pc - b0];                                   \
            gid = (int)s_gid[seg][pc - b0]; }

        #define LOADROW() {                                               \
            const float* __restrict__ grow = vals + gid * 343;            \
            _Pragma("unroll")                                             \
            for (int k = 0; k < 42; ++k) rbuf[k] = grow[sub + 8 * k];     \
            rbuf[42] = (sub < 7) ? grow[336 + sub] : 0.0f; }

        FETCH(grp); LOADROW();
        float* __restrict__ myv = &s_v[grp][0];

        for (int c = 0; c < nch; ++c) {
            // Commit staged row (chunk c) to this group's LDS row.
            #pragma unroll
            for (int k = 0; k < 42; ++k) myv[sub + 8 * k] = rbuf[k];
            if (sub < 7) myv[336 + sub] = rbuf[42];

            const float4 prc  = pr;
            const int    segc = seg;
            const float  gw   = (32 * c + grp < CT) ? prc.w : 0.0f;

            // Prefetch next chunk's pair+row while computing this one.
            if (c + 1 < nch) { FETCH(32 * (c + 1) + grp); LOADROW(); }

            float dy2[7], dz2[7];                    // static-indexed -> regs
            #pragma unroll
            for (int j = 0; j < 7; ++j) { const float d = prc.y - j * STEP; dy2[j] = d * d; }
            #pragma unroll
            for (int l = 0; l < 7; ++l) { const float d = prc.z - l * STEP; dz2[l] = d * d; }

            const int   slab = (sub < 7) ? sub : 6;
            const float dxv  = prc.x - slab * STEP;
            const float dx2  = (sub < 7) ? dxv * dxv : 4.0f;   // sub==7 -> wt 0
            const float* __restrict__ vrow = myv + slab * 49;

            float ws = 0.0f, vs = 0.0f;
            #pragma unroll
            for (int j = 0; j < 7; ++j) {
                const float dxy = dx2 + dy2[j];
                #pragma unroll
                for (int l = 0; l < 7; ++l) {
                    const float d2 = dxy + dz2[l];
                    const float wt = (d2 <= 1.0f) ? FSQRT(d2) : 0.0f;
                    ws += wt;
                    vs  = fmaf(wt, vrow[j * 7 + l], vs);
                }
            }
            #pragma unroll
            for (int o = 4; o >= 1; o >>= 1) {
                ws += __shfl_xor(ws, o);
                vs += __shfl_xor(vs, o);
            }
            const float interp = (ws > 0.0f) ? (vs / ws) : 0.0f;
            if (sub == 0) {
                const float contrib = interp * gw;
                if (segc < 2) acc0 += contrib;
                else          acc1 += contrib;
            }
        }
        #undef FETCH
        #undef LOADROW
    }

    // Block reduction: butterfly per wave, then cross-wave via LDS.
    #pragma unroll
    for (int o = 32; o >= 1; o >>= 1) {
        acc0 += __shfl_xor(acc0, o);
        acc1 += __shfl_xor(acc1, o);
    }
    if (lane == 0) { s_red[w][0] = acc0; s_red[w][1] = acc1; }
    __syncthreads();
    if (t < 2) {
        const float nm = s_red[0][t] + s_red[1][t] + s_red[2][t] + s_red[3][t];
        const float dn = (t == 0) ? den0 : den1;
        out[(bid << 1) + t] = (dn > 0.0f) ? (nm / dn) : 0.0f;
    }
}

extern "C" void kernel_launch(void* const* d_in, const int* in_sizes, int n_in,
                              void* d_out, int out_size, void* d_ws, size_t ws_size,
                              hipStream_t stream) {
    const float* points  = (const float*)d_in[0];   // (1024,3)
    const float* centers = (const float*)d_in[1];   // (512,3)
    const float* scales  = (const float*)d_in[2];   // (512,)
    const float* vals    = (const float*)d_in[3];   // (512,7,7,7)
    float* out = (float*)d_out;                     // (1024,)

    msdf_fused<<<NBLK, TPB, 0, stream>>>(points, centers, scales, vals, out);
}